// Round 1
// baseline (776.961 us; speedup 1.0000x reference)
//
#include <hip/hip_runtime.h>
#include <math.h>

#define NN 4096
#define DD 256
#define MM 8192
#define NSPLIT 16
#define COLS_PER (MM / NSPLIT) /* 512 */
#define BM 64
#define BN 64
#define KC 128

// ---------------------------------------------------------------------------
// Kernel 1: s_pos[p] = 2 * dot(z_i[p], z_j[p])   (sim of positive pair)
// ---------------------------------------------------------------------------
__global__ __launch_bounds__(256) void k_spos(const float* __restrict__ zi,
                                              const float* __restrict__ zj,
                                              float* __restrict__ spos) {
  int p = blockIdx.x * 4 + (threadIdx.x >> 6);
  int l = threadIdx.x & 63;
  const float4* a = (const float4*)(zi + (size_t)p * DD);
  const float4* b = (const float4*)(zj + (size_t)p * DD);
  float4 av = a[l], bv = b[l];
  float d = av.x * bv.x + av.y * bv.y + av.z * bv.z + av.w * bv.w;
#pragma unroll
  for (int o = 32; o > 0; o >>= 1) d += __shfl_down(d, o);
  if (l == 0) spos[p] = d * 2.0f;
}

// ---------------------------------------------------------------------------
// Kernel 2: fused sim-GEMM + row reduction.
// Each block: 64 rows x 512-column slice. Accumulates per row:
//   Z = sum_{k != row} exp(s - 2),  cnt = #{k: s > s_pos(row)}
// Partials written per (row, split).
// ---------------------------------------------------------------------------
__global__ __launch_bounds__(256) void k_main(const float* __restrict__ zi,
                                              const float* __restrict__ zj,
                                              const float* __restrict__ spos,
                                              float* __restrict__ pz,
                                              float* __restrict__ pcnt) {
  __shared__ float At[KC][BM];
  __shared__ float Bt[KC][BN];
  const int split = blockIdx.x;
  const int r0 = blockIdx.y * BM;
  const int c0 = split * COLS_PER;
  const int tid = threadIdx.x;
  const int ty = tid >> 4, tx = tid & 15;

  float Zacc[4] = {0.f, 0.f, 0.f, 0.f};
  int cnt[4] = {0, 0, 0, 0};
  float sp[4];
#pragma unroll
  for (int ri = 0; ri < 4; ++ri) {
    int R = r0 + ty * 4 + ri;
    sp[ri] = spos[(R < NN) ? R : (R - NN)];
  }

  for (int t = 0; t < COLS_PER / BN; ++t) {
    const int cc = c0 + t * BN;
    float a00 = 0.f, a01 = 0.f, a02 = 0.f, a03 = 0.f;
    float a10 = 0.f, a11 = 0.f, a12 = 0.f, a13 = 0.f;
    float a20 = 0.f, a21 = 0.f, a22 = 0.f, a23 = 0.f;
    float a30 = 0.f, a31 = 0.f, a32 = 0.f, a33 = 0.f;

    for (int kc = 0; kc < DD; kc += KC) {
      __syncthreads();  // protect LDS from readers of previous tile/chunk
#pragma unroll
      for (int rep = 0; rep < 8; ++rep) {
        int idx = rep * 256 + tid;
        int k4 = (idx & 7) | ((idx >> 9) << 3);  // 0..31
        int rl = (idx >> 3) & 63;                // 0..63
        int kk = k4 * 4;
        {
          int grow = r0 + rl;
          const float* src = (grow < NN) ? (zi + (size_t)grow * DD)
                                         : (zj + (size_t)(grow - NN) * DD);
          float4 v = *(const float4*)(src + kc + kk);
          At[kk + 0][rl] = v.x;
          At[kk + 1][rl] = v.y;
          At[kk + 2][rl] = v.z;
          At[kk + 3][rl] = v.w;
        }
        {
          int gcol = cc + rl;
          const float* srcb = (gcol < NN) ? (zi + (size_t)gcol * DD)
                                          : (zj + (size_t)(gcol - NN) * DD);
          float4 v = *(const float4*)(srcb + kc + kk);
          Bt[kk + 0][rl] = v.x;
          Bt[kk + 1][rl] = v.y;
          Bt[kk + 2][rl] = v.z;
          Bt[kk + 3][rl] = v.w;
        }
      }
      __syncthreads();
#pragma unroll 8
      for (int k = 0; k < KC; ++k) {
        float4 a = *(const float4*)&At[k][ty * 4];
        float4 b = *(const float4*)&Bt[k][tx * 4];
        a00 += a.x * b.x; a01 += a.x * b.y; a02 += a.x * b.z; a03 += a.x * b.w;
        a10 += a.y * b.x; a11 += a.y * b.y; a12 += a.y * b.z; a13 += a.y * b.w;
        a20 += a.z * b.x; a21 += a.z * b.y; a22 += a.z * b.z; a23 += a.z * b.w;
        a30 += a.w * b.x; a31 += a.w * b.y; a32 += a.w * b.z; a33 += a.w * b.w;
      }
    }

    // epilogue for this 64x64 tile
    float accv[4][4] = {{a00, a01, a02, a03},
                        {a10, a11, a12, a13},
                        {a20, a21, a22, a23},
                        {a30, a31, a32, a33}};
#pragma unroll
    for (int ri = 0; ri < 4; ++ri) {
      int R = r0 + ty * 4 + ri;
#pragma unroll
      for (int ci = 0; ci < 4; ++ci) {
        int Cg = cc + tx * 4 + ci;
        if (R != Cg) {
          float s = accv[ri][ci] * 2.0f;  // /TEMPERATURE
          Zacc[ri] += __expf(s - 2.0f);   // fixed shift; |s| <= 2
          cnt[ri] += (s > sp[ri]) ? 1 : 0;
        }
      }
    }
  }

  // reduce across the 16 threads (tx) sharing each row
#pragma unroll
  for (int ri = 0; ri < 4; ++ri) {
    float z = Zacc[ri];
    float c = (float)cnt[ri];
#pragma unroll
    for (int o = 1; o <= 8; o <<= 1) {
      z += __shfl_xor(z, o);
      c += __shfl_xor(c, o);
    }
    if (tx == 0) {
      int R = r0 + ty * 4 + ri;
      pz[(size_t)R * NSPLIT + split] = z;
      pcnt[(size_t)R * NSPLIT + split] = c;
    }
  }
}

// ---------------------------------------------------------------------------
// Kernel 3: combine split partials -> per-row loss L and top-k indicator T
// ---------------------------------------------------------------------------
__global__ __launch_bounds__(256) void k_combine(const float* __restrict__ spos,
                                                 const float* __restrict__ pz,
                                                 const float* __restrict__ pcnt,
                                                 float* __restrict__ Lb,
                                                 float* __restrict__ Tb) {
  int i = blockIdx.x * 256 + threadIdx.x;
  float Z = 0.f, c = 0.f;
#pragma unroll
  for (int s = 0; s < NSPLIT; ++s) {
    Z += pz[(size_t)i * NSPLIT + s];
    c += pcnt[(size_t)i * NSPLIT + s];
  }
  float sp = spos[(i < NN) ? i : (i - NN)];
  float p = __expf(sp - 2.0f) / Z;          // softmax prob at the label
  Lb[i] = logf(8193.0f) - p;                // log(M+1) - p_label
  Tb[i] = (c < 2048.0f) ? 1.0f : 0.0f;      // s_pos within top-2048 of row i
}

// ---------------------------------------------------------------------------
// Kernel 4: final weighted reduction
// final = [ (0.3M + 0.7 + 0.4*2048)*sum(L) + 0.7*sum_{j<N} L_j
//           - 0.4*sum_{j<N} L_j*T_{N+j} ] / M^2
// ---------------------------------------------------------------------------
__global__ __launch_bounds__(256) void k_final(const float* __restrict__ Lb,
                                               const float* __restrict__ Tb,
                                               float* __restrict__ out) {
  __shared__ float sA[256], sB[256], sC[256];
  int tid = threadIdx.x;
  float a = 0.f, b = 0.f, c = 0.f;
  for (int i = tid; i < MM; i += 256) {
    float L = Lb[i];
    a += L;
    if (i < NN) {
      b += L;
      c += L * Tb[NN + i];
    }
  }
  sA[tid] = a; sB[tid] = b; sC[tid] = c;
  __syncthreads();
  for (int o = 128; o > 0; o >>= 1) {
    if (tid < o) {
      sA[tid] += sA[tid + o];
      sB[tid] += sB[tid + o];
      sC[tid] += sC[tid + o];
    }
    __syncthreads();
  }
  if (tid == 0) {
    float A = sA[0], B = sB[0], C = sC[0];
    out[0] = (3277.5f * A + 0.7f * B - 0.4f * C) *
             (1.0f / ((float)MM * (float)MM));
  }
}

// ---------------------------------------------------------------------------
extern "C" void kernel_launch(void* const* d_in, const int* in_sizes, int n_in,
                              void* d_out, int out_size, void* d_ws, size_t ws_size,
                              hipStream_t stream) {
  const float* zi = (const float*)d_in[0];
  const float* zj = (const float*)d_in[1];
  float* ws = (float*)d_ws;
  float* spos = ws;                          // NN
  float* pz = ws + NN;                       // MM*NSPLIT
  float* pcnt = pz + (size_t)MM * NSPLIT;    // MM*NSPLIT
  float* Lb = pcnt + (size_t)MM * NSPLIT;    // MM
  float* Tb = Lb + MM;                       // MM
  float* outf = (float*)d_out;

  hipLaunchKernelGGL(k_spos, dim3(NN / 4), dim3(256), 0, stream, zi, zj, spos);
  hipLaunchKernelGGL(k_main, dim3(NSPLIT, MM / BM), dim3(256), 0, stream,
                     zi, zj, spos, pz, pcnt);
  hipLaunchKernelGGL(k_combine, dim3(MM / 256), dim3(256), 0, stream,
                     spos, pz, pcnt, Lb, Tb);
  hipLaunchKernelGGL(k_final, dim3(1), dim3(256), 0, stream, Lb, Tb, outf);
}

// Round 2
// 127.092 us; speedup vs baseline: 6.1134x; 6.1134x over previous
//
#include <hip/hip_runtime.h>
#include <hip/hip_bf16.h>
#include <math.h>

#define NN 4096
#define DD 256
#define MM 8192

typedef short bf16x8 __attribute__((ext_vector_type(8)));
typedef float f32x4 __attribute__((ext_vector_type(4)));

// ---------------------------------------------------------------------------
// Kernel 0: convert z (fp32, two halves) -> zb bf16 [8192][256]
// ---------------------------------------------------------------------------
__global__ __launch_bounds__(256) void k_convert(const float* __restrict__ zi,
                                                 const float* __restrict__ zj,
                                                 ushort* __restrict__ zb) {
  int idx = blockIdx.x * 256 + threadIdx.x;  // 4 elems per thread
  int e0 = idx * 4;
  int row = e0 >> 8;
  const float* src = (row < NN) ? (zi + (size_t)row * DD)
                                : (zj + (size_t)(row - NN) * DD);
  float4 v = *(const float4*)(src + (e0 & 255));
  __hip_bfloat16 h0 = __float2bfloat16(v.x);
  __hip_bfloat16 h1 = __float2bfloat16(v.y);
  __hip_bfloat16 h2 = __float2bfloat16(v.z);
  __hip_bfloat16 h3 = __float2bfloat16(v.w);
  ushort4 o;
  o.x = *(ushort*)&h0; o.y = *(ushort*)&h1;
  o.z = *(ushort*)&h2; o.w = *(ushort*)&h3;
  *(ushort4*)(zb + e0) = o;
}

// ---------------------------------------------------------------------------
// Kernel 1: s_pos[p] = 2 * dot(z_i[p], z_j[p])  (fp32)
// ---------------------------------------------------------------------------
__global__ __launch_bounds__(256) void k_spos(const float* __restrict__ zi,
                                              const float* __restrict__ zj,
                                              float* __restrict__ spos) {
  int p = blockIdx.x * 4 + (threadIdx.x >> 6);
  int l = threadIdx.x & 63;
  const float4* a = (const float4*)(zi + (size_t)p * DD);
  const float4* b = (const float4*)(zj + (size_t)p * DD);
  float4 av = a[l], bv = b[l];
  float d = av.x * bv.x + av.y * bv.y + av.z * bv.z + av.w * bv.w;
#pragma unroll
  for (int o = 32; o > 0; o >>= 1) d += __shfl_down(d, o);
  if (l == 0) spos[p] = d * 2.0f;
}

// ---------------------------------------------------------------------------
// Kernel 2: bf16 MFMA sim-GEMM, fused epilogue:
//   Zrow[i] += sum_{k != i} exp(s_ik - 2)   (s = 2*dot, |s| <= 2)
//   Cnt[i]  += #{k != i: s_ik > s_pos_i}    (rows i >= NN only)
// 128x128 tile per block, 4 waves (2x2), 64x64 per wave, 16x16x32 MFMA.
// LDS XOR-swizzled (3-bit row XOR on 16B slots) -> b128 reads at bank floor.
// ---------------------------------------------------------------------------
__global__ __launch_bounds__(256, 4) void k_sim(const ushort* __restrict__ zb,
                                                const float* __restrict__ spos,
                                                float* __restrict__ Zrow,
                                                int* __restrict__ Cnt) {
  __shared__ __align__(16) ushort As[128 * 64];
  __shared__ __align__(16) ushort Bs[128 * 64];
  const int bi = blockIdx.y, bj = blockIdx.x;
  const int r0 = bi * 128, c0 = bj * 128;
  const int tid = threadIdx.x;
  const int l = tid & 63, w = tid >> 6;
  const int wr = w >> 1, wc = w & 1;
  const int g = l >> 4, li = l & 15;
  const bool doCnt = (r0 >= NN);

  f32x4 acc[4][4] = {};

  for (int kc = 0; kc < DD; kc += 64) {
    __syncthreads();
#pragma unroll
    for (int p = 0; p < 4; ++p) {
      int idx = p * 256 + tid;
      int row = idx >> 3, ko8 = idx & 7;
      // swizzled ushort offset: row*64 + ((ko8 ^ (row&7)) * 8)
      int so = row * 64 + ((ko8 ^ (row & 7)) << 3);
      const ushort* ga = zb + (size_t)(r0 + row) * DD + kc + ko8 * 8;
      *(float4*)(As + so) = *(const float4*)ga;
      const ushort* gb = zb + (size_t)(c0 + row) * DD + kc + ko8 * 8;
      *(float4*)(Bs + so) = *(const float4*)gb;
    }
    __syncthreads();
#pragma unroll
    for (int ks = 0; ks < 2; ++ks) {
      bf16x8 af[4], bfr[4];
#pragma unroll
      for (int mi = 0; mi < 4; ++mi) {
        int r = wr * 64 + mi * 16 + li;
        int kb7 = ((ks << 2) | g) ^ (r & 7);  // 16B slot within 128B row
        af[mi] = *(const bf16x8*)(As + r * 64 + (kb7 << 3));
      }
#pragma unroll
      for (int ni = 0; ni < 4; ++ni) {
        int r = wc * 64 + ni * 16 + li;
        int kb7 = ((ks << 2) | g) ^ (r & 7);
        bfr[ni] = *(const bf16x8*)(Bs + r * 64 + (kb7 << 3));
      }
#pragma unroll
      for (int mi = 0; mi < 4; ++mi)
#pragma unroll
        for (int ni = 0; ni < 4; ++ni)
          acc[mi][ni] = __builtin_amdgcn_mfma_f32_16x16x32_bf16(
              af[mi], bfr[ni], acc[mi][ni], 0, 0, 0);
    }
  }

  // epilogue: C/D layout: col = li, row = g*4 + reg  (per 16x16 tile)
#pragma unroll
  for (int mi = 0; mi < 4; ++mi) {
    int Rbase = r0 + wr * 64 + mi * 16 + g * 4;
    float zs[4] = {0.f, 0.f, 0.f, 0.f};
    int cs[4] = {0, 0, 0, 0};
    float sph[4];
#pragma unroll
    for (int reg = 0; reg < 4; ++reg)
      sph[reg] = doCnt ? 0.5f * spos[Rbase + reg - NN] : 3.0e38f;
#pragma unroll
    for (int ni = 0; ni < 4; ++ni) {
      int C = c0 + wc * 64 + ni * 16 + li;
#pragma unroll
      for (int reg = 0; reg < 4; ++reg) {
        float a = acc[mi][ni][reg];
        float e = __expf(2.0f * a - 2.0f);
        if (Rbase + reg != C) {
          zs[reg] += e;
          cs[reg] += (a > sph[reg]) ? 1 : 0;
        }
      }
    }
#pragma unroll
    for (int reg = 0; reg < 4; ++reg) {
      float z = zs[reg];
      int c = cs[reg];
#pragma unroll
      for (int o = 1; o <= 8; o <<= 1) {
        z += __shfl_xor(z, o);
        c += __shfl_xor(c, o);
      }
      if (li == 0) {
        atomicAdd(&Zrow[Rbase + reg], z);
        if (doCnt) atomicAdd(&Cnt[Rbase + reg], c);
      }
    }
  }
}

// ---------------------------------------------------------------------------
// Kernel 3: per-row loss L and top-k indicator T
// ---------------------------------------------------------------------------
__global__ __launch_bounds__(256) void k_combine(const float* __restrict__ spos,
                                                 const float* __restrict__ Zrow,
                                                 const int* __restrict__ Cnt,
                                                 float* __restrict__ Lb,
                                                 float* __restrict__ Tb) {
  int i = blockIdx.x * 256 + threadIdx.x;
  float Z = Zrow[i];
  float sp = spos[(i < NN) ? i : (i - NN)];
  float p = __expf(sp - 2.0f) / Z;
  Lb[i] = logf(8193.0f) - p;
  Tb[i] = (i >= NN) ? ((Cnt[i] < 2048) ? 1.0f : 0.0f) : 0.0f;
}

// ---------------------------------------------------------------------------
// Kernel 4: final weighted reduction
// final = [ (0.3M + 0.7 + 0.4*2048)*sum(L) + 0.7*sum_{j<N} L_j
//           - 0.4*sum_{j<N} L_j*T_{N+j} ] / M^2
// ---------------------------------------------------------------------------
__global__ __launch_bounds__(256) void k_final(const float* __restrict__ Lb,
                                               const float* __restrict__ Tb,
                                               float* __restrict__ out) {
  __shared__ float sA[256], sB[256], sC[256];
  int tid = threadIdx.x;
  float a = 0.f, b = 0.f, c = 0.f;
  for (int i = tid; i < MM; i += 256) {
    float L = Lb[i];
    a += L;
    if (i < NN) {
      b += L;
      c += L * Tb[NN + i];
    }
  }
  sA[tid] = a; sB[tid] = b; sC[tid] = c;
  __syncthreads();
  for (int o = 128; o > 0; o >>= 1) {
    if (tid < o) {
      sA[tid] += sA[tid + o];
      sB[tid] += sB[tid + o];
      sC[tid] += sC[tid + o];
    }
    __syncthreads();
  }
  if (tid == 0) {
    out[0] = (3277.5f * sA[0] + 0.7f * sB[0] - 0.4f * sC[0]) *
             (1.0f / ((float)MM * (float)MM));
  }
}

// ---------------------------------------------------------------------------
extern "C" void kernel_launch(void* const* d_in, const int* in_sizes, int n_in,
                              void* d_out, int out_size, void* d_ws, size_t ws_size,
                              hipStream_t stream) {
  const float* zi = (const float*)d_in[0];
  const float* zj = (const float*)d_in[1];
  float* ws = (float*)d_ws;
  float* spos = ws;                       // NN floats
  float* Zrow = ws + NN;                  // MM floats
  int* Cnt = (int*)(ws + NN + MM);        // MM ints
  float* Lb = ws + NN + 2 * MM;           // MM
  float* Tb = ws + NN + 3 * MM;           // MM
  ushort* zb = (ushort*)(ws + NN + 4 * MM);  // MM*DD bf16 (4 MB)
  float* outf = (float*)d_out;

  // zero the accumulators (harness does not re-poison between replays)
  hipMemsetAsync(Zrow, 0, (size_t)2 * MM * sizeof(float), stream);

  hipLaunchKernelGGL(k_convert, dim3(MM * DD / 1024), dim3(256), 0, stream,
                     zi, zj, zb);
  hipLaunchKernelGGL(k_spos, dim3(NN / 4), dim3(256), 0, stream, zi, zj, spos);
  hipLaunchKernelGGL(k_sim, dim3(MM / 128, MM / 128), dim3(256), 0, stream,
                     zb, spos, Zrow, Cnt);
  hipLaunchKernelGGL(k_combine, dim3(MM / 256), dim3(256), 0, stream,
                     spos, Zrow, Cnt, Lb, Tb);
  hipLaunchKernelGGL(k_final, dim3(1), dim3(256), 0, stream, Lb, Tb, outf);
}

// Round 3
// 78.418 us; speedup vs baseline: 9.9079x; 1.6207x over previous
//
#include <hip/hip_runtime.h>
#include <hip/hip_bf16.h>
#include <math.h>

#define NN 4096
#define DD 256
#define MM 8192
#define CSPLIT 16
#define CW 512  /* cols per block */
#define CT 64   /* cols per tile  */
#define NCT 8   /* tiles per block */

typedef short bf16x8 __attribute__((ext_vector_type(8)));
typedef float f32x4 __attribute__((ext_vector_type(4)));

// ---------------------------------------------------------------------------
// Kernel 0: convert z (fp32, two halves) -> zb bf16 [8192][256], and
//           spos[p] = 2 * dot(z_i[p], z_j[p]) in fp32 (rows < NN only).
// One block = 4 rows (64 lanes per row).
// ---------------------------------------------------------------------------
__global__ __launch_bounds__(256) void k_convert(const float* __restrict__ zi,
                                                 const float* __restrict__ zj,
                                                 ushort* __restrict__ zb,
                                                 float* __restrict__ spos) {
  int row = blockIdx.x * 4 + (threadIdx.x >> 6);
  int l = threadIdx.x & 63;
  const float* src = (row < NN) ? (zi + (size_t)row * DD)
                                : (zj + (size_t)(row - NN) * DD);
  float4 v = *(const float4*)(src + l * 4);
  __hip_bfloat16 h0 = __float2bfloat16(v.x);
  __hip_bfloat16 h1 = __float2bfloat16(v.y);
  __hip_bfloat16 h2 = __float2bfloat16(v.z);
  __hip_bfloat16 h3 = __float2bfloat16(v.w);
  ushort4 o;
  o.x = *(ushort*)&h0; o.y = *(ushort*)&h1;
  o.z = *(ushort*)&h2; o.w = *(ushort*)&h3;
  *(ushort4*)(zb + (size_t)row * DD + l * 4) = o;
  if (row < NN) {
    float4 u = *(const float4*)(zj + (size_t)row * DD + l * 4);
    float d = v.x * u.x + v.y * u.y + v.z * u.z + v.w * u.w;
#pragma unroll
    for (int off = 32; off > 0; off >>= 1) d += __shfl_down(d, off);
    if (l == 0) spos[row] = 2.0f * d;
  }
}

// ---------------------------------------------------------------------------
// Kernel 1: bf16 MFMA sim-GEMM, fully fused row-reduction.
// Block = 256 threads (4 waves), owns 128 rows x 512 cols, K = 256 (full).
// A-panel: 64 VGPR/thread, loaded once from L2 (no LDS for A).
// B: 64-col x 256-K tiles via global_load_lds (width 16), double-buffered,
//    source-pre-swizzled so linear LDS + swizzled ds_read_b128 is
//    bank-conflict-free (rule #21 / m201 pattern).
// Z[row] and cnt[row] accumulate in registers across all 8 col-tiles;
// one shuffle-reduce + partial write per block. No atomics, no memset.
// ---------------------------------------------------------------------------
__global__ __launch_bounds__(256, 2) void k_sim(const ushort* __restrict__ zb,
                                                const float* __restrict__ spos,
                                                float* __restrict__ pz,
                                                float* __restrict__ pc) {
  __shared__ __align__(16) ushort Bs[2][CT][DD];
  const int cs = blockIdx.x;
  const int c0 = cs * CW;
  const int rp = blockIdx.y;
  const int tid = threadIdx.x;
  const int w = tid >> 6, l = tid & 63;
  const int li = l & 15, g = l >> 4;
  const int rowbase = rp * 128 + w * 32;
  const bool doCnt = (rp * 128 >= NN);

  // --- stage issue: wave w stages its 16 cols of tile ct into buf ---
  auto issue = [&](int ct, int buf) {
    const int colbase = w * 16;
#pragma unroll
    for (int j = 0; j < 8; ++j) {
      int col_l = colbase + j * 2 + (l >> 5);
      int slot_lin = l & 31;
      int slot_g = (slot_lin & 24) | ((slot_lin ^ col_l) & 7);
      const ushort* gp =
          zb + (size_t)(c0 + ct * CT + col_l) * DD + slot_g * 8;
      __builtin_amdgcn_global_load_lds(
          (const __attribute__((address_space(1))) void*)gp,
          (__attribute__((address_space(3))) void*)&Bs[buf][colbase + j * 2][0],
          16, 0, 0);
    }
  };

  issue(0, 0);

  // --- A fragments: rows rowbase..rowbase+31, full K, in registers ---
  bf16x8 af[2][8];
#pragma unroll
  for (int mi = 0; mi < 2; ++mi)
#pragma unroll
    for (int ks = 0; ks < 8; ++ks)
      af[mi][ks] = *(const bf16x8*)(zb + (size_t)(rowbase + mi * 16 + li) * DD +
                                    ks * 32 + g * 8);

  float sph[2][4];
  if (doCnt) {
#pragma unroll
    for (int mi = 0; mi < 2; ++mi)
#pragma unroll
      for (int reg = 0; reg < 4; ++reg)
        sph[mi][reg] =
            0.5f * spos[rowbase + mi * 16 + g * 4 + reg - NN];
  }

  float zs[2][4] = {};
  int cn[2][4] = {};

  for (int ct = 0; ct < NCT; ++ct) {
    __syncthreads();  // compiler drains vmcnt -> buf[ct&1] staged & visible
    if (ct + 1 < NCT) issue(ct + 1, (ct + 1) & 1);

    const ushort* bb = &Bs[ct & 1][0][0];
    f32x4 acc[2][4] = {};
#pragma unroll
    for (int ks = 0; ks < 8; ++ks) {
      bf16x8 bfr[4];
#pragma unroll
      for (int ni = 0; ni < 4; ++ni) {
        int col_l = ni * 16 + li;
        int slot = ks * 4 + g;
        int sw = (slot & 24) | ((slot ^ col_l) & 7);
        bfr[ni] = *(const bf16x8*)(bb + col_l * DD + sw * 8);
      }
#pragma unroll
      for (int mi = 0; mi < 2; ++mi)
#pragma unroll
        for (int ni = 0; ni < 4; ++ni)
          acc[mi][ni] = __builtin_amdgcn_mfma_f32_16x16x32_bf16(
              af[mi][ks], bfr[ni], acc[mi][ni], 0, 0, 0);
    }

    // fused epilogue for this tile: accumulate into row registers
#pragma unroll
    for (int mi = 0; mi < 2; ++mi) {
#pragma unroll
      for (int ni = 0; ni < 4; ++ni) {
        int C = c0 + ct * CT + ni * 16 + li;
#pragma unroll
        for (int reg = 0; reg < 4; ++reg) {
          int R = rowbase + mi * 16 + g * 4 + reg;
          float a = acc[mi][ni][reg];
          float e = __expf(2.0f * a - 2.0f);  // |s|<=2, fixed shift
          zs[mi][reg] += (R != C) ? e : 0.0f;
          if (doCnt)
            cn[mi][reg] += ((a > sph[mi][reg]) && (R != C)) ? 1 : 0;
        }
      }
    }
  }

  // one reduction per block: over the 16 li-lanes sharing each row
#pragma unroll
  for (int mi = 0; mi < 2; ++mi)
#pragma unroll
    for (int reg = 0; reg < 4; ++reg) {
      float z = zs[mi][reg];
      float c = (float)cn[mi][reg];
#pragma unroll
      for (int off = 1; off <= 8; off <<= 1) {
        z += __shfl_xor(z, off);
        c += __shfl_xor(c, off);
      }
      if (li == 0) {
        int row = rowbase + mi * 16 + g * 4 + reg;
        pz[(size_t)row * CSPLIT + cs] = z;
        if (doCnt) pc[(size_t)row * CSPLIT + cs] = c;
      }
    }
}

// ---------------------------------------------------------------------------
// Kernel 2: combine partials + final weighted reduction
// final = [ (0.3M + 0.7 + 0.4*2048)*sum(L) + 0.7*sum_{j<N} L_j
//           - 0.4*sum_{j<N} L_j*T_{N+j} ] / M^2,  L_i = log(M+1) - p_label_i
// ---------------------------------------------------------------------------
__global__ __launch_bounds__(256) void k_final(const float* __restrict__ spos,
                                               const float* __restrict__ pz,
                                               const float* __restrict__ pc,
                                               float* __restrict__ out) {
  __shared__ float sA[256], sB[256], sC[256];
  int tid = threadIdx.x;
  float a = 0.f, b = 0.f, c = 0.f;
  for (int i = tid; i < MM; i += 256) {
    float Z = 0.f;
    const float4* p4 = (const float4*)(pz + (size_t)i * CSPLIT);
#pragma unroll
    for (int s = 0; s < 4; ++s) {
      float4 v = p4[s];
      Z += v.x + v.y + v.z + v.w;
    }
    float sp = spos[(i < NN) ? i : (i - NN)];
    float L = logf(8193.0f) - __expf(sp - 2.0f) / Z;
    a += L;
    if (i < NN) {
      float cv = 0.f;
      const float4* q4 = (const float4*)(pc + (size_t)(NN + i) * CSPLIT);
#pragma unroll
      for (int s = 0; s < 4; ++s) {
        float4 v = q4[s];
        cv += v.x + v.y + v.z + v.w;
      }
      b += L;
      c += (cv < 2048.0f) ? L : 0.0f;
    }
  }
  sA[tid] = a; sB[tid] = b; sC[tid] = c;
  __syncthreads();
  for (int off = 128; off > 0; off >>= 1) {
    if (tid < off) {
      sA[tid] += sA[tid + off];
      sB[tid] += sB[tid + off];
      sC[tid] += sC[tid + off];
    }
    __syncthreads();
  }
  if (tid == 0) {
    out[0] = (3277.5f * sA[0] + 0.7f * sB[0] - 0.4f * sC[0]) *
             (1.0f / ((float)MM * (float)MM));
  }
}

// ---------------------------------------------------------------------------
extern "C" void kernel_launch(void* const* d_in, const int* in_sizes, int n_in,
                              void* d_out, int out_size, void* d_ws, size_t ws_size,
                              hipStream_t stream) {
  const float* zi = (const float*)d_in[0];
  const float* zj = (const float*)d_in[1];
  float* wsf = (float*)d_ws;
  ushort* zb = (ushort*)wsf;                     // MM*DD bf16 = 4 MB
  float* spos = wsf + (size_t)MM * DD / 2;       // NN floats
  float* pz = spos + NN;                         // MM*CSPLIT floats
  float* pc = pz + (size_t)MM * CSPLIT;          // MM*CSPLIT floats
  float* outf = (float*)d_out;

  hipLaunchKernelGGL(k_convert, dim3(MM / 4), dim3(256), 0, stream,
                     zi, zj, zb, spos);
  hipLaunchKernelGGL(k_sim, dim3(CSPLIT, MM / 128), dim3(256), 0, stream,
                     zb, spos, pz, pc);
  hipLaunchKernelGGL(k_final, dim3(1), dim3(256), 0, stream, spos, pz, pc, outf);
}